// Round 2
// baseline (823.359 us; speedup 1.0000x reference)
//
#include <hip/hip_runtime.h>
#include <hip/hip_bf16.h>

typedef unsigned short u16t;
typedef __attribute__((ext_vector_type(8))) short bf16x8;
typedef __attribute__((ext_vector_type(4))) float f32x4;

__device__ __forceinline__ float bf2f(u16t u) {
  union { unsigned int i; float f; } v; v.i = ((unsigned int)u) << 16; return v.f;
}
__device__ __forceinline__ float bitsf(unsigned int u) {
  union { unsigned int i; float f; } v; v.i = u; return v.f;
}
__device__ __forceinline__ u16t f2bf(float f) {
  union { float f; unsigned int i; } v; v.f = f;
  return (u16t)((v.i + 0x7fffu + ((v.i >> 16) & 1u)) >> 16);
}
// Packed f32x2 -> bf16x2 (RNE, lo -> low 16 bits) via compiler intrinsic.
// r6 used asm("v_cvt_pk_bf16_f32") which produced NaNs; the intrinsic path is
// the m240-recommended form (compiler emits/schedules the packed convert).
__device__ __forceinline__ unsigned int cvtpk(float lo, float hi) {
  float2 f; f.x = lo; f.y = hi;
  union { __hip_bfloat162 b; unsigned int u; } v;
  v.b = __float22bfloat162_rn(f);
  return v.u;
}
__device__ __forceinline__ float sigm(float x) { return 1.0f / (1.0f + __expf(-x)); }
__device__ __forceinline__ float tanh_f(float x) { return 1.0f - 2.0f / (__expf(2.0f * x) + 1.0f); }
__device__ __forceinline__ float lrelu(float x) { return x > 0.0f ? x : 0.2f * x; }

__device__ __forceinline__ float ldf(const void* p, long i, bool isbf) {
  return isbf ? bf2f(((const u16t*)p)[i]) : ((const float*)p)[i];
}
__device__ __forceinline__ bf16x8 ld8(const void* p, long i, bool isbf) {
  if (isbf) return *reinterpret_cast<const bf16x8*>((const u16t*)p + i);
  const float* f = (const float*)p + i;
  bf16x8 r;
  #pragma unroll
  for (int j = 0; j < 8; ++j) r[j] = (short)f2bf(f[j]);
  return r;
}
__device__ __forceinline__ bool sniff_bf(const void* h_g) {
  bool isbf = true;
  #pragma unroll
  for (int i = 0; i < 16; ++i) {
    u16t u = ((const u16t*)h_g)[2 * i];
    int e = (u >> 7) & 0xFF;
    if (e < 100 || e > 142) isbf = false;
  }
  return isbf;
}

#define MFMA16(a, b, c) __builtin_amdgcn_mfma_f32_16x16x32_bf16((a), (b), (c), 0, 0, 0)

#define DDIM 128
#define SD 136   // s/a tiles: 64 rows x 128 + 8 pad
#define ST 72    // mT / attn tiles: +8 pad
// Three rotating 18432-B regions (roles: s_cur / mT->s_next / a), u16-element offsets
#define R0_OFF 0
#define R1_OFF 9216
#define R2_OFF 18432
#define AT_OFF 27648
#define NLDS   32256   // 64512 B (+768 B floats) -> 2 blocks/CU

// SD-tile XOR swizzle (r6): element (row, feat) lives at row*SD + (feat ^ fs(row)),
// fs(row) = ((row>>2)&3)<<3 -- the two "quad" bits of the row XOR'd into 16B-unit
// index. The per-r u16 scatter stores (GEMM2 / snew: rows quad*4+r) previously hit
// 16 banks 4-way (row stride 272B only separates quad&1); the XOR injects both quad
// bits into bank bits 2-3 -> 32 banks, 2 lanes/bank (same-dword pair = free, m136).
// b128 frag reads stay balanced (involution on bits 3-4): use qx in place of quad*8.
#define SWZ(row, feat) ((row) * SD + ((feat) ^ ((((row) >> 2) & 3) << 3)))

// ws layout (bf16), fragment-major: one wave's fragment = 1 KB contiguous
#define WS_W_OFF   0
#define WS_IH_OFF  16384
#define WS_HH_OFF  65536
#define WS_M1_OFF  114688
#define WS_ELEMS   122880

__global__ __launch_bounds__(256) void prep(
    const void* __restrict__ h_g, const void* __restrict__ w_g,
    const void* __restrict__ wih_g, const void* __restrict__ whh_g,
    const void* __restrict__ m1w_g, u16t* __restrict__ ws) {
  const bool isbf = sniff_bf(h_g);
  const int idx = blockIdx.x * 256 + threadIdx.x;
  if (idx >= WS_ELEMS) return;
  float val;
  if (idx < WS_IH_OFF) {
    int t = idx;
    int j = t & 7, lane = (t >> 3) & 63, ks = (t >> 9) & 3, wv = t >> 11;
    val = ldf(w_g, (long)(ks * 32 + (lane >> 4) * 8 + j) * DDIM + wv * 16 + (lane & 15), isbf);
  } else if (idx < WS_HH_OFF) {
    int t = idx - WS_IH_OFF;
    int j = t & 7, lane = (t >> 3) & 63, ks = (t >> 9) & 3, rem = t >> 11;
    int g = rem % 3, wv = rem / 3;
    val = ldf(wih_g, (long)(g * 128 + wv * 16 + (lane & 15)) * DDIM + ks * 32 + (lane >> 4) * 8 + j, isbf);
  } else if (idx < WS_M1_OFF) {
    int t = idx - WS_HH_OFF;
    int j = t & 7, lane = (t >> 3) & 63, ks = (t >> 9) & 3, rem = t >> 11;
    int g = rem % 3, wv = rem / 3;
    val = ldf(whh_g, (long)(g * 128 + wv * 16 + (lane & 15)) * DDIM + ks * 32 + (lane >> 4) * 8 + j, isbf);
  } else {
    int t = idx - WS_M1_OFF;
    int j = t & 7, lane = (t >> 3) & 63, ks = (t >> 9) & 3, wv = t >> 11;
    val = ldf(m1w_g, (long)(ks * 32 + (lane >> 4) * 8 + j) * 64 + wv * 16 + (lane & 15), isbf);
  }
  ws[idx] = f2bf(val);
}

// DESIGN NOTE (r2-r5): allocator pins 128 VGPRs; demand above that spills into
// the hot loop AND removes load-hoisting slack (every L2 B-frag load = exposed
// stall -> r5's 1220 us at 6.6% MfmaUtil). This version targets peak live
// ~115 VGPRs: gate phases split (rz then n, rg/zg packed bf16 pairs), s/h
// carried packed in regs, 3-region LDS rotation -> 2 barriers/step, no sh_h.
// r6/r7: packed bf16 converts for ALL f32->bf16 sites (~300 VALU ops/thread/
// step saved) + SD-tile XOR swizzle (see SWZ) for the u16 scatter conflicts.
template <bool WSOK>
__global__ __launch_bounds__(512) void fignn(
    const void* __restrict__ h_g, const void* __restrict__ asrc_g,
    const void* __restrict__ adst_g, const void* __restrict__ w_g,
    const void* __restrict__ bias_g, const void* __restrict__ wih_g,
    const void* __restrict__ whh_g, const void* __restrict__ bih_g,
    const void* __restrict__ bhh_g, const void* __restrict__ m1w_g,
    const void* __restrict__ m1b_g, const void* __restrict__ m2w_g,
    const void* __restrict__ m2b_g, const int* __restrict__ steps_p,
    const u16t* __restrict__ ws_g, void* __restrict__ out_g) {
  __shared__ __align__(16) u16t lds[NLDS];
  __shared__ __align__(16) float ldsf[192];
  u16t* sh_at = lds + AT_OFF;
  float* f_src = ldsf;
  float* f_dst = ldsf + 64;
  float* f_wv  = ldsf + 128;

  const int tid  = threadIdx.x;
  const int wv   = tid >> 6;
  const int lane = tid & 63;
  const int quad = lane >> 4;
  const int lrow = lane & 15;
  const int col  = wv * 16 + lrow;  // feature column (N-split across 8 waves)
  const int b    = blockIdx.x;
  // swizzle helpers: qx replaces quad*8 in b128 frag reads (row = *+lrow);
  // fc replaces col in u16 scatter writes (row = *+quad*4+r).
  const int qx = (quad ^ ((lrow >> 2) & 3)) << 3;
  const int fc = col ^ (quad << 3);

  const bool isbf = sniff_bf(h_g);

  u16t* s_c = lds + R0_OFF;  // current s
  u16t* s_m = lds + R1_OFF;  // mT, then s_next
  u16t* s_a = lds + R2_OFF;  // message a

  // ---- stage h -> s_c (s0 = h), swizzled ----
  const long hb = (long)b * (64 * DDIM);
  #pragma unroll
  for (int v = 0; v < 2; ++v) {
    int e = (tid + v * 512) * 8;
    int r = e >> 7, c = e & 127;
    *reinterpret_cast<bf16x8*>(s_c + SWZ(r, c)) = ld8(h_g, hb + e, isbf);
  }

  // ---- per-thread packed h / s registers (2 bf16 per uint) ----
  unsigned int sreg2[8], hreg2[8];
  #pragma unroll
  for (int mt = 0; mt < 4; ++mt) {
    #pragma unroll
    for (int half = 0; half < 2; ++half) {
      long i0 = hb + (long)(mt * 16 + quad * 4 + half * 2) * DDIM + col;
      u16t lo, hi;
      if (isbf) {
        lo = ((const u16t*)h_g)[i0];
        hi = ((const u16t*)h_g)[i0 + DDIM];
      } else {
        lo = f2bf(((const float*)h_g)[i0]);
        hi = f2bf(((const float*)h_g)[i0 + DDIM]);
      }
      unsigned int p = (unsigned int)lo | ((unsigned int)hi << 16);
      hreg2[mt * 2 + half] = p;
      sreg2[mt * 2 + half] = p;
    }
  }

  const float msg_b = ldf(bias_g, col, isbf);
  const float bsum_r = ldf(bih_g, col, isbf) + ldf(bhh_g, col, isbf);
  const float bsum_z = ldf(bih_g, 128 + col, isbf) + ldf(bhh_g, 128 + col, isbf);
  const float b_in   = ldf(bih_g, 256 + col, isbf);
  const float b_hn   = ldf(bhh_g, 256 + col, isbf);
  int steps = *steps_p;
  if (steps < 1 || steps > 64) steps = 3;
  __syncthreads();

  // ---- attention dots (128 threads: 2 per node) ----
  if (tid < 128) {
    const int node = tid >> 1, half = tid & 1;
    float sa = 0.f, da = 0.f;
    #pragma unroll
    for (int k = half * 64; k < half * 64 + 64; k += 8) {
      bf16x8 hv = *reinterpret_cast<const bf16x8*>(s_c + SWZ(node, k));
      #pragma unroll
      for (int j = 0; j < 8; ++j) {
        float hf = bf2f((u16t)hv[j]);
        sa += hf * ldf(asrc_g, k + j, isbf);
        da += hf * ldf(adst_g, k + j, isbf);
      }
    }
    sa += __shfl_xor(sa, 1);
    da += __shfl_xor(da, 1);
    if (half == 0) { f_src[node] = sa; f_dst[node] = da; }
  }
  __syncthreads();
  // ---- masked-diagonal softmax, 8 threads per row ----
  {
    const int row = tid >> 3, sub = tid & 7;
    const float si = f_src[row];
    float vals[8];
    float mx = 0.0f;  // diagonal (masked) entry is exactly 0, part of the row
    #pragma unroll
    for (int u = 0; u < 8; ++u) {
      int j = sub + u * 8;
      float vv = (j == row) ? 0.0f : lrelu(si + f_dst[j]);
      vals[u] = vv;
      mx = fmaxf(mx, vv);
    }
    mx = fmaxf(mx, __shfl_xor(mx, 1));
    mx = fmaxf(mx, __shfl_xor(mx, 2));
    mx = fmaxf(mx, __shfl_xor(mx, 4));
    float sum = 0.f;
    #pragma unroll
    for (int u = 0; u < 8; ++u) { vals[u] = __expf(vals[u] - mx); sum += vals[u]; }
    sum += __shfl_xor(sum, 1);
    sum += __shfl_xor(sum, 2);
    sum += __shfl_xor(sum, 4);
    float inv = 1.0f / sum;
    #pragma unroll
    for (int u = 0; u < 8; u += 2) {
      unsigned int pk = cvtpk(vals[u] * inv, vals[u + 1] * inv);
      sh_at[row * ST + sub + u * 8] = (u16t)pk;
      sh_at[row * ST + sub + (u + 1) * 8] = (u16t)(pk >> 16);
    }
  }
  __syncthreads();

  // ---- message-passing + GRU steps (2 barriers/step) ----
  for (int it = 0; it < steps; ++it) {
    // GEMM1: mT[col][*] = (s @ w)[:, col] -> s_m (wave-local, packed)
    {
      f32x4 macc[4] = {{0,0,0,0},{0,0,0,0},{0,0,0,0},{0,0,0,0}};
      #pragma unroll
      for (int ks = 0; ks < 4; ++ks) {
        bf16x8 bw;
        if constexpr (WSOK) {
          bw = *reinterpret_cast<const bf16x8*>(ws_g + WS_W_OFF + (((wv * 4 + ks) * 64 + lane) << 3));
        } else {
          #pragma unroll
          for (int j = 0; j < 8; ++j)
            bw[j] = (short)f2bf(ldf(w_g, (long)(ks * 32 + quad * 8 + j) * DDIM + col, isbf));
        }
        #pragma unroll
        for (int mt = 0; mt < 4; ++mt) {
          bf16x8 af = *reinterpret_cast<const bf16x8*>(s_c + (mt * 16 + lrow) * SD + ks * 32 + qx);
          macc[mt] = MFMA16(af, bw, macc[mt]);
        }
      }
      #pragma unroll
      for (int mt = 0; mt < 4; ++mt) {
        uint2 pk2;
        pk2.x = cvtpk(macc[mt][0], macc[mt][1]);
        pk2.y = cvtpk(macc[mt][2], macc[mt][3]);
        *reinterpret_cast<uint2*>(s_m + col * ST + mt * 16 + quad * 4) = pk2;
      }
    }
    // GEMM2: a[:, col] = (attn @ m)[:, col] + bias -> s_a (intra-wave mT read)
    #pragma unroll
    for (int mt = 0; mt < 4; ++mt) {
      f32x4 acc = {0.f, 0.f, 0.f, 0.f};
      #pragma unroll
      for (int ks = 0; ks < 2; ++ks) {
        bf16x8 af  = *reinterpret_cast<const bf16x8*>(sh_at + (mt * 16 + lrow) * ST + ks * 32 + quad * 8);
        bf16x8 bfv = *reinterpret_cast<const bf16x8*>(s_m + col * ST + ks * 32 + quad * 8);
        acc = MFMA16(af, bfv, acc);
      }
      unsigned int p01 = cvtpk(acc[0] + msg_b, acc[1] + msg_b);
      unsigned int p23 = cvtpk(acc[2] + msg_b, acc[3] + msg_b);
      const int rb = (mt * 16 + quad * 4) * SD + fc;
      s_a[rb         ] = (u16t)p01;
      s_a[rb + SD    ] = (u16t)(p01 >> 16);
      s_a[rb + 2 * SD] = (u16t)p23;
      s_a[rb + 3 * SD] = (u16t)(p23 >> 16);
    }
    __syncthreads();  // (1) a ready; all mT reads done

    // Phase rz: r,z gate pre-activations (gi+gh combined), packed bf16 pairs
    unsigned int rg2[8], zg2[8];
    {
      f32x4 ar[4] = {{0,0,0,0},{0,0,0,0},{0,0,0,0},{0,0,0,0}};
      f32x4 az[4] = {{0,0,0,0},{0,0,0,0},{0,0,0,0},{0,0,0,0}};
      #pragma unroll
      for (int ks = 0; ks < 4; ++ks) {
        bf16x8 fr[4];
        #pragma unroll
        for (int mt = 0; mt < 4; ++mt)
          fr[mt] = *reinterpret_cast<const bf16x8*>(s_a + (mt * 16 + lrow) * SD + ks * 32 + qx);
        bf16x8 bw;
        if constexpr (WSOK) bw = *reinterpret_cast<const bf16x8*>(ws_g + WS_IH_OFF + ((((wv * 3 + 0) * 4 + ks) * 64 + lane) << 3));
        else bw = ld8(wih_g, (long)(0 * 128 + col) * DDIM + ks * 32 + quad * 8, isbf);
        #pragma unroll
        for (int mt = 0; mt < 4; ++mt) ar[mt] = MFMA16(fr[mt], bw, ar[mt]);
        if constexpr (WSOK) bw = *reinterpret_cast<const bf16x8*>(ws_g + WS_IH_OFF + ((((wv * 3 + 1) * 4 + ks) * 64 + lane) << 3));
        else bw = ld8(wih_g, (long)(1 * 128 + col) * DDIM + ks * 32 + quad * 8, isbf);
        #pragma unroll
        for (int mt = 0; mt < 4; ++mt) az[mt] = MFMA16(fr[mt], bw, az[mt]);
        #pragma unroll
        for (int mt = 0; mt < 4; ++mt)
          fr[mt] = *reinterpret_cast<const bf16x8*>(s_c + (mt * 16 + lrow) * SD + ks * 32 + qx);
        if constexpr (WSOK) bw = *reinterpret_cast<const bf16x8*>(ws_g + WS_HH_OFF + ((((wv * 3 + 0) * 4 + ks) * 64 + lane) << 3));
        else bw = ld8(whh_g, (long)(0 * 128 + col) * DDIM + ks * 32 + quad * 8, isbf);
        #pragma unroll
        for (int mt = 0; mt < 4; ++mt) ar[mt] = MFMA16(fr[mt], bw, ar[mt]);
        if constexpr (WSOK) bw = *reinterpret_cast<const bf16x8*>(ws_g + WS_HH_OFF + ((((wv * 3 + 1) * 4 + ks) * 64 + lane) << 3));
        else bw = ld8(whh_g, (long)(1 * 128 + col) * DDIM + ks * 32 + quad * 8, isbf);
        #pragma unroll
        for (int mt = 0; mt < 4; ++mt) az[mt] = MFMA16(fr[mt], bw, az[mt]);
      }
      #pragma unroll
      for (int mt = 0; mt < 4; ++mt) {
        rg2[mt * 2 + 0] = cvtpk(sigm(ar[mt][0] + bsum_r), sigm(ar[mt][1] + bsum_r));
        rg2[mt * 2 + 1] = cvtpk(sigm(ar[mt][2] + bsum_r), sigm(ar[mt][3] + bsum_r));
        zg2[mt * 2 + 0] = cvtpk(sigm(az[mt][0] + bsum_z), sigm(az[mt][1] + bsum_z));
        zg2[mt * 2 + 1] = cvtpk(sigm(az[mt][2] + bsum_z), sigm(az[mt][3] + bsum_z));
      }
    }
    // Phase n + pointwise GRU + snew -> s_m (mT dead after barrier 1)
    {
      f32x4 ain[4] = {{0,0,0,0},{0,0,0,0},{0,0,0,0},{0,0,0,0}};
      f32x4 ahn[4] = {{0,0,0,0},{0,0,0,0},{0,0,0,0},{0,0,0,0}};
      #pragma unroll
      for (int ks = 0; ks < 4; ++ks) {
        bf16x8 fr[4];
        #pragma unroll
        for (int mt = 0; mt < 4; ++mt)
          fr[mt] = *reinterpret_cast<const bf16x8*>(s_a + (mt * 16 + lrow) * SD + ks * 32 + qx);
        bf16x8 bw;
        if constexpr (WSOK) bw = *reinterpret_cast<const bf16x8*>(ws_g + WS_IH_OFF + ((((wv * 3 + 2) * 4 + ks) * 64 + lane) << 3));
        else bw = ld8(wih_g, (long)(2 * 128 + col) * DDIM + ks * 32 + quad * 8, isbf);
        #pragma unroll
        for (int mt = 0; mt < 4; ++mt) ain[mt] = MFMA16(fr[mt], bw, ain[mt]);
        #pragma unroll
        for (int mt = 0; mt < 4; ++mt)
          fr[mt] = *reinterpret_cast<const bf16x8*>(s_c + (mt * 16 + lrow) * SD + ks * 32 + qx);
        if constexpr (WSOK) bw = *reinterpret_cast<const bf16x8*>(ws_g + WS_HH_OFF + ((((wv * 3 + 2) * 4 + ks) * 64 + lane) << 3));
        else bw = ld8(whh_g, (long)(2 * 128 + col) * DDIM + ks * 32 + quad * 8, isbf);
        #pragma unroll
        for (int mt = 0; mt < 4; ++mt) ahn[mt] = MFMA16(fr[mt], bw, ahn[mt]);
      }
      #pragma unroll
      for (int mt = 0; mt < 4; ++mt) {
        #pragma unroll
        for (int pr = 0; pr < 2; ++pr) {
          unsigned int rp = rg2[mt * 2 + pr], zp = zg2[mt * 2 + pr];
          unsigned int sp = sreg2[mt * 2 + pr], hp = hreg2[mt * 2 + pr];
          float r0 = bitsf(rp << 16), r1 = bitsf(rp & 0xffff0000u);
          float z0 = bitsf(zp << 16), z1 = bitsf(zp & 0xffff0000u);
          float ng0 = tanh_f(ain[mt][2 * pr + 0] + b_in + r0 * (ahn[mt][2 * pr + 0] + b_hn));
          float ng1 = tanh_f(ain[mt][2 * pr + 1] + b_in + r1 * (ahn[mt][2 * pr + 1] + b_hn));
          float sn0 = (1.0f - z0) * ng0 + z0 * bitsf(sp << 16) + bitsf(hp << 16);
          float sn1 = (1.0f - z1) * ng1 + z1 * bitsf(sp & 0xffff0000u) + bitsf(hp & 0xffff0000u);
          unsigned int pk = cvtpk(sn0, sn1);
          sreg2[mt * 2 + pr] = pk;
          const int rb = (mt * 16 + quad * 4 + pr * 2) * SD + fc;
          s_m[rb     ] = (u16t)pk;
          s_m[rb + SD] = (u16t)(pk >> 16);
        }
      }
    }
    __syncthreads();  // (2) s_next ready
    u16t* t = s_c; s_c = s_m; s_m = s_a; s_a = t;  // rotate roles
  }

  // ---- readout: out[c] = sum_n (s@mlp2_w + b2)[n] * (s@mlp1_w + b1)[n][c] ----
  f32x4 oacc[4] = {{0,0,0,0},{0,0,0,0},{0,0,0,0},{0,0,0,0}};
  if (wv < 4) {
    #pragma unroll
    for (int ks = 0; ks < 4; ++ks) {
      bf16x8 bw;
      if constexpr (WSOK) {
        bw = *reinterpret_cast<const bf16x8*>(ws_g + WS_M1_OFF + (((wv * 4 + ks) * 64 + lane) << 3));
      } else {
        #pragma unroll
        for (int j = 0; j < 8; ++j)
          bw[j] = (short)f2bf(ldf(m1w_g, (long)(ks * 32 + quad * 8 + j) * 64 + col, isbf));
      }
      #pragma unroll
      for (int mt = 0; mt < 4; ++mt) {
        bf16x8 af = *reinterpret_cast<const bf16x8*>(s_c + (mt * 16 + lrow) * SD + ks * 32 + qx);
        oacc[mt] = MFMA16(af, bw, oacc[mt]);
      }
    }
    const float b1c = ldf(m1b_g, col, isbf);
    #pragma unroll
    for (int mt = 0; mt < 4; ++mt)
      #pragma unroll
      for (int r = 0; r < 4; ++r) oacc[mt][r] += b1c;
  } else if (wv == 4) {
    const int fs4 = ((lane >> 2) & 3) << 3;
    float acc = 0.f;
    #pragma unroll
    for (int k = 0; k < 128; k += 8) {
      bf16x8 sv = *reinterpret_cast<const bf16x8*>(s_c + lane * SD + (k ^ fs4));
      #pragma unroll
      for (int j = 0; j < 8; ++j) acc += bf2f((u16t)sv[j]) * ldf(m2w_g, k + j, isbf);
    }
    f_wv[lane] = acc + ldf(m2b_g, 0, isbf);
  }
  __syncthreads();
  if (wv < 4) {
    float p = 0.f;
    #pragma unroll
    for (int mt = 0; mt < 4; ++mt)
      #pragma unroll
      for (int r = 0; r < 4; ++r)
        p += f_wv[mt * 16 + quad * 4 + r] * oacc[mt][r];
    p += __shfl_xor(p, 16);
    p += __shfl_xor(p, 32);
    if (quad == 0) {
      if (isbf) ((u16t*)out_g)[(long)b * 64 + col] = f2bf(p);
      else      ((float*)out_g)[(long)b * 64 + col] = p;
    }
  }
}

extern "C" void kernel_launch(void* const* d_in, const int* in_sizes, int n_in,
                              void* d_out, int out_size, void* d_ws, size_t ws_size,
                              hipStream_t stream) {
  (void)in_sizes; (void)n_in; (void)out_size;
  // d_in order: h, adj(unused), a_src, a_dst, w, bias, W_ih, W_hh, b_ih, b_hh,
  //             mlp1_w, mlp1_b, mlp2_w, mlp2_b, steps
  const bool wsok = ws_size >= (size_t)WS_ELEMS * 2;
  if (wsok) {
    prep<<<dim3((WS_ELEMS + 255) / 256), dim3(256), 0, stream>>>(
        d_in[0], d_in[4], d_in[6], d_in[7], d_in[10], (u16t*)d_ws);
    fignn<true><<<dim3(4096), dim3(512), 0, stream>>>(
        d_in[0], d_in[2], d_in[3], d_in[4], d_in[5], d_in[6], d_in[7], d_in[8],
        d_in[9], d_in[10], d_in[11], d_in[12], d_in[13], (const int*)d_in[14],
        (const u16t*)d_ws, d_out);
  } else {
    fignn<false><<<dim3(4096), dim3(512), 0, stream>>>(
        d_in[0], d_in[2], d_in[3], d_in[4], d_in[5], d_in[6], d_in[7], d_in[8],
        d_in[9], d_in[10], d_in[11], d_in[12], d_in[13], (const int*)d_in[14],
        (const u16t*)d_ws, d_out);
  }
}

// Round 3
// 646.678 us; speedup vs baseline: 1.2732x; 1.2732x over previous
//
#include <hip/hip_runtime.h>
#include <hip/hip_bf16.h>

typedef unsigned short u16t;
typedef __attribute__((ext_vector_type(8))) short bf16x8;
typedef __attribute__((ext_vector_type(4))) float f32x4;

__device__ __forceinline__ float bf2f(u16t u) {
  union { unsigned int i; float f; } v; v.i = ((unsigned int)u) << 16; return v.f;
}
__device__ __forceinline__ float bitsf(unsigned int u) {
  union { unsigned int i; float f; } v; v.i = u; return v.f;
}
__device__ __forceinline__ u16t f2bf(float f) {
  union { float f; unsigned int i; } v; v.f = f;
  return (u16t)((v.i + 0x7fffu + ((v.i >> 16) & 1u)) >> 16);
}
// Packed f32x2 -> bf16x2 (RNE, lo -> low 16 bits). memcpy (not union) so SROA
// keeps it in registers -- the r7 union form created allocas (scratch: +205 MB
// WRITE_SIZE). Intrinsic path is numerically verified (r7 passed).
__device__ __forceinline__ unsigned int cvtpk(float lo, float hi) {
  float2 f; f.x = lo; f.y = hi;
  __hip_bfloat162 b = __float22bfloat162_rn(f);
  unsigned int r; __builtin_memcpy(&r, &b, 4); return r;
}
// v_rcp_f32 (~1e-7 rel err, far below bf16 rounding) replaces IEEE f32 divide
// (~10-op div_scale/fmas/fixup sequence) in the activations.
__device__ __forceinline__ float frcp(float x) { return __builtin_amdgcn_rcpf(x); }
__device__ __forceinline__ float sigm(float x) { return frcp(1.0f + __expf(-x)); }
__device__ __forceinline__ float tanh_f(float x) { return 1.0f - 2.0f * frcp(__expf(2.0f * x) + 1.0f); }
__device__ __forceinline__ float lrelu(float x) { return x > 0.0f ? x : 0.2f * x; }

__device__ __forceinline__ float ldf(const void* p, long i, bool isbf) {
  return isbf ? bf2f(((const u16t*)p)[i]) : ((const float*)p)[i];
}
__device__ __forceinline__ bf16x8 ld8(const void* p, long i, bool isbf) {
  if (isbf) return *reinterpret_cast<const bf16x8*>((const u16t*)p + i);
  const float* f = (const float*)p + i;
  bf16x8 r;
  #pragma unroll
  for (int j = 0; j < 8; ++j) r[j] = (short)f2bf(f[j]);
  return r;
}
__device__ __forceinline__ bool sniff_bf(const void* h_g) {
  bool isbf = true;
  #pragma unroll
  for (int i = 0; i < 16; ++i) {
    u16t u = ((const u16t*)h_g)[2 * i];
    int e = (u >> 7) & 0xFF;
    if (e < 100 || e > 142) isbf = false;
  }
  return isbf;
}

#define MFMA16(a, b, c) __builtin_amdgcn_mfma_f32_16x16x32_bf16((a), (b), (c), 0, 0, 0)

#define DDIM 128
#define SD 136   // s/a tiles: 64 rows x 128 + 8 pad (2-way bank alias = free)
#define ST 72    // mT / attn tiles: +8 pad
// Three rotating 18432-B regions (roles: s_cur / mT->s_next / a), u16-element offsets
#define R0_OFF 0
#define R1_OFF 9216
#define R2_OFF 18432
#define AT_OFF 27648
#define NLDS   32256   // 64512 B (+768 B floats) -> 2 blocks/CU

// ws layout (bf16), fragment-major: one wave's fragment = 1 KB contiguous
#define WS_W_OFF   0
#define WS_IH_OFF  16384
#define WS_HH_OFF  65536
#define WS_M1_OFF  114688
#define WS_ELEMS   122880

__global__ __launch_bounds__(256) void prep(
    const void* __restrict__ h_g, const void* __restrict__ w_g,
    const void* __restrict__ wih_g, const void* __restrict__ whh_g,
    const void* __restrict__ m1w_g, u16t* __restrict__ ws) {
  const bool isbf = sniff_bf(h_g);
  const int idx = blockIdx.x * 256 + threadIdx.x;
  if (idx >= WS_ELEMS) return;
  float val;
  if (idx < WS_IH_OFF) {
    int t = idx;
    int j = t & 7, lane = (t >> 3) & 63, ks = (t >> 9) & 3, wv = t >> 11;
    val = ldf(w_g, (long)(ks * 32 + (lane >> 4) * 8 + j) * DDIM + wv * 16 + (lane & 15), isbf);
  } else if (idx < WS_HH_OFF) {
    int t = idx - WS_IH_OFF;
    int j = t & 7, lane = (t >> 3) & 63, ks = (t >> 9) & 3, rem = t >> 11;
    int g = rem % 3, wv = rem / 3;
    val = ldf(wih_g, (long)(g * 128 + wv * 16 + (lane & 15)) * DDIM + ks * 32 + (lane >> 4) * 8 + j, isbf);
  } else if (idx < WS_M1_OFF) {
    int t = idx - WS_HH_OFF;
    int j = t & 7, lane = (t >> 3) & 63, ks = (t >> 9) & 3, rem = t >> 11;
    int g = rem % 3, wv = rem / 3;
    val = ldf(whh_g, (long)(g * 128 + wv * 16 + (lane & 15)) * DDIM + ks * 32 + (lane >> 4) * 8 + j, isbf);
  } else {
    int t = idx - WS_M1_OFF;
    int j = t & 7, lane = (t >> 3) & 63, ks = (t >> 9) & 3, wv = t >> 11;
    val = ldf(m1w_g, (long)(ks * 32 + (lane >> 4) * 8 + j) * 64 + wv * 16 + (lane & 15), isbf);
  }
  ws[idx] = f2bf(val);
}

// DESIGN NOTE (r2-r8): allocator pins 128 VGPRs; demand above that spills into
// the hot loop (r5: full 4-mt gate merge = 1220 us). r8 finding: kernel is
// phase-serialized on the LDS pipe (barrier lockstep; MfmaUtil 12 / VALU 35 /
// conflicts 7% -- nothing saturated, VALU shaves didn't move time). Dominant
// traffic was rz+n phases re-reading the same s_a/s_c fragments twice
// (64 of 96 b128 reads/wave/step). Fix: fuse gates per mt-PAIR -- accumulate
// all 6 gate GEMM contributions in one ks loop (acc = 2mt x {ar,az,ain,ahn}
// = 32 regs, same as old rz phase), pointwise immediately, each fragment read
// ONCE. 96 -> 64 reads/wave/step. Weight loads 24->48 (L2-resident, cheap).
// r6/r7 lessons: bank-conflict swizzle = no effect (reverted); cvtpk must be
// memcpy-form (union = scratch); keep packed bf16 converts everywhere.
template <bool WSOK>
__global__ __launch_bounds__(512) void fignn(
    const void* __restrict__ h_g, const void* __restrict__ asrc_g,
    const void* __restrict__ adst_g, const void* __restrict__ w_g,
    const void* __restrict__ bias_g, const void* __restrict__ wih_g,
    const void* __restrict__ whh_g, const void* __restrict__ bih_g,
    const void* __restrict__ bhh_g, const void* __restrict__ m1w_g,
    const void* __restrict__ m1b_g, const void* __restrict__ m2w_g,
    const void* __restrict__ m2b_g, const int* __restrict__ steps_p,
    const u16t* __restrict__ ws_g, void* __restrict__ out_g) {
  __shared__ __align__(16) u16t lds[NLDS];
  __shared__ __align__(16) float ldsf[192];
  u16t* sh_at = lds + AT_OFF;
  float* f_src = ldsf;
  float* f_dst = ldsf + 64;
  float* f_wv  = ldsf + 128;

  const int tid  = threadIdx.x;
  const int wv   = tid >> 6;
  const int lane = tid & 63;
  const int quad = lane >> 4;
  const int lrow = lane & 15;
  const int col  = wv * 16 + lrow;  // feature column (N-split across 8 waves)
  const int b    = blockIdx.x;

  const bool isbf = sniff_bf(h_g);

  u16t* s_c = lds + R0_OFF;  // current s
  u16t* s_m = lds + R1_OFF;  // mT, then s_next
  u16t* s_a = lds + R2_OFF;  // message a

  // ---- stage h -> s_c (s0 = h) ----
  const long hb = (long)b * (64 * DDIM);
  #pragma unroll
  for (int v = 0; v < 2; ++v) {
    int e = (tid + v * 512) * 8;
    int r = e >> 7, c = e & 127;
    *reinterpret_cast<bf16x8*>(s_c + r * SD + c) = ld8(h_g, hb + e, isbf);
  }

  // ---- per-thread packed h / s registers (2 bf16 per uint) ----
  unsigned int sreg2[8], hreg2[8];
  #pragma unroll
  for (int mt = 0; mt < 4; ++mt) {
    #pragma unroll
    for (int half = 0; half < 2; ++half) {
      long i0 = hb + (long)(mt * 16 + quad * 4 + half * 2) * DDIM + col;
      u16t lo, hi;
      if (isbf) {
        lo = ((const u16t*)h_g)[i0];
        hi = ((const u16t*)h_g)[i0 + DDIM];
      } else {
        lo = f2bf(((const float*)h_g)[i0]);
        hi = f2bf(((const float*)h_g)[i0 + DDIM]);
      }
      unsigned int p = (unsigned int)lo | ((unsigned int)hi << 16);
      hreg2[mt * 2 + half] = p;
      sreg2[mt * 2 + half] = p;
    }
  }

  const float msg_b = ldf(bias_g, col, isbf);
  const float bsum_r = ldf(bih_g, col, isbf) + ldf(bhh_g, col, isbf);
  const float bsum_z = ldf(bih_g, 128 + col, isbf) + ldf(bhh_g, 128 + col, isbf);
  const float b_in   = ldf(bih_g, 256 + col, isbf);
  const float b_hn   = ldf(bhh_g, 256 + col, isbf);
  int steps = *steps_p;
  if (steps < 1 || steps > 64) steps = 3;
  __syncthreads();

  // ---- attention dots (128 threads: 2 per node) ----
  if (tid < 128) {
    const int node = tid >> 1, half = tid & 1;
    float sa = 0.f, da = 0.f;
    #pragma unroll
    for (int k = half * 64; k < half * 64 + 64; k += 8) {
      bf16x8 hv = *reinterpret_cast<const bf16x8*>(s_c + node * SD + k);
      #pragma unroll
      for (int j = 0; j < 8; ++j) {
        float hf = bf2f((u16t)hv[j]);
        sa += hf * ldf(asrc_g, k + j, isbf);
        da += hf * ldf(adst_g, k + j, isbf);
      }
    }
    sa += __shfl_xor(sa, 1);
    da += __shfl_xor(da, 1);
    if (half == 0) { f_src[node] = sa; f_dst[node] = da; }
  }
  __syncthreads();
  // ---- masked-diagonal softmax, 8 threads per row ----
  {
    const int row = tid >> 3, sub = tid & 7;
    const float si = f_src[row];
    float vals[8];
    float mx = 0.0f;  // diagonal (masked) entry is exactly 0, part of the row
    #pragma unroll
    for (int u = 0; u < 8; ++u) {
      int j = sub + u * 8;
      float vv = (j == row) ? 0.0f : lrelu(si + f_dst[j]);
      vals[u] = vv;
      mx = fmaxf(mx, vv);
    }
    mx = fmaxf(mx, __shfl_xor(mx, 1));
    mx = fmaxf(mx, __shfl_xor(mx, 2));
    mx = fmaxf(mx, __shfl_xor(mx, 4));
    float sum = 0.f;
    #pragma unroll
    for (int u = 0; u < 8; ++u) { vals[u] = __expf(vals[u] - mx); sum += vals[u]; }
    sum += __shfl_xor(sum, 1);
    sum += __shfl_xor(sum, 2);
    sum += __shfl_xor(sum, 4);
    float inv = frcp(sum);
    #pragma unroll
    for (int u = 0; u < 8; u += 2) {
      unsigned int pk = cvtpk(vals[u] * inv, vals[u + 1] * inv);
      sh_at[row * ST + sub + u * 8] = (u16t)pk;
      sh_at[row * ST + sub + (u + 1) * 8] = (u16t)(pk >> 16);
    }
  }
  __syncthreads();

  // ---- message-passing + GRU steps (2 barriers/step) ----
  for (int it = 0; it < steps; ++it) {
    // GEMM1: mT[col][*] = (s @ w)[:, col] -> s_m (wave-local, packed)
    {
      f32x4 macc[4] = {{0,0,0,0},{0,0,0,0},{0,0,0,0},{0,0,0,0}};
      #pragma unroll
      for (int ks = 0; ks < 4; ++ks) {
        bf16x8 bw;
        if constexpr (WSOK) {
          bw = *reinterpret_cast<const bf16x8*>(ws_g + WS_W_OFF + (((wv * 4 + ks) * 64 + lane) << 3));
        } else {
          #pragma unroll
          for (int j = 0; j < 8; ++j)
            bw[j] = (short)f2bf(ldf(w_g, (long)(ks * 32 + quad * 8 + j) * DDIM + col, isbf));
        }
        #pragma unroll
        for (int mt = 0; mt < 4; ++mt) {
          bf16x8 af = *reinterpret_cast<const bf16x8*>(s_c + (mt * 16 + lrow) * SD + ks * 32 + quad * 8);
          macc[mt] = MFMA16(af, bw, macc[mt]);
        }
      }
      #pragma unroll
      for (int mt = 0; mt < 4; ++mt) {
        uint2 pk2;
        pk2.x = cvtpk(macc[mt][0], macc[mt][1]);
        pk2.y = cvtpk(macc[mt][2], macc[mt][3]);
        *reinterpret_cast<uint2*>(s_m + col * ST + mt * 16 + quad * 4) = pk2;
      }
    }
    // GEMM2: a[:, col] = (attn @ m)[:, col] + bias -> s_a (intra-wave mT read)
    #pragma unroll
    for (int mt = 0; mt < 4; ++mt) {
      f32x4 acc = {0.f, 0.f, 0.f, 0.f};
      #pragma unroll
      for (int ks = 0; ks < 2; ++ks) {
        bf16x8 af  = *reinterpret_cast<const bf16x8*>(sh_at + (mt * 16 + lrow) * ST + ks * 32 + quad * 8);
        bf16x8 bfv = *reinterpret_cast<const bf16x8*>(s_m + col * ST + ks * 32 + quad * 8);
        acc = MFMA16(af, bfv, acc);
      }
      unsigned int p01 = cvtpk(acc[0] + msg_b, acc[1] + msg_b);
      unsigned int p23 = cvtpk(acc[2] + msg_b, acc[3] + msg_b);
      const int rb = (mt * 16 + quad * 4) * SD + col;
      s_a[rb         ] = (u16t)p01;
      s_a[rb + SD    ] = (u16t)(p01 >> 16);
      s_a[rb + 2 * SD] = (u16t)p23;
      s_a[rb + 3 * SD] = (u16t)(p23 >> 16);
    }
    __syncthreads();  // (1) a ready; all mT reads done

    // Fused gate phase: per mt-PAIR accumulate all 6 gate GEMM contributions
    // (r/z share a-side+h-side accumulators), then pointwise GRU immediately.
    // Each s_a / s_c fragment is read exactly ONCE per step.
    #pragma unroll
    for (int p = 0; p < 2; ++p) {
      f32x4 ar[2]  = {{0,0,0,0},{0,0,0,0}};
      f32x4 az[2]  = {{0,0,0,0},{0,0,0,0}};
      f32x4 ain[2] = {{0,0,0,0},{0,0,0,0}};
      f32x4 ahn[2] = {{0,0,0,0},{0,0,0,0}};
      #pragma unroll
      for (int ks = 0; ks < 4; ++ks) {
        bf16x8 fa[2], fh[2];
        #pragma unroll
        for (int m = 0; m < 2; ++m) {
          const int mt = p * 2 + m;
          fa[m] = *reinterpret_cast<const bf16x8*>(s_a + (mt * 16 + lrow) * SD + ks * 32 + quad * 8);
          fh[m] = *reinterpret_cast<const bf16x8*>(s_c + (mt * 16 + lrow) * SD + ks * 32 + quad * 8);
        }
        bf16x8 bw;
        // a-side: Wih r, z, n
        if constexpr (WSOK) bw = *reinterpret_cast<const bf16x8*>(ws_g + WS_IH_OFF + ((((wv * 3 + 0) * 4 + ks) * 64 + lane) << 3));
        else bw = ld8(wih_g, (long)(0 * 128 + col) * DDIM + ks * 32 + quad * 8, isbf);
        #pragma unroll
        for (int m = 0; m < 2; ++m) ar[m] = MFMA16(fa[m], bw, ar[m]);
        if constexpr (WSOK) bw = *reinterpret_cast<const bf16x8*>(ws_g + WS_IH_OFF + ((((wv * 3 + 1) * 4 + ks) * 64 + lane) << 3));
        else bw = ld8(wih_g, (long)(1 * 128 + col) * DDIM + ks * 32 + quad * 8, isbf);
        #pragma unroll
        for (int m = 0; m < 2; ++m) az[m] = MFMA16(fa[m], bw, az[m]);
        if constexpr (WSOK) bw = *reinterpret_cast<const bf16x8*>(ws_g + WS_IH_OFF + ((((wv * 3 + 2) * 4 + ks) * 64 + lane) << 3));
        else bw = ld8(wih_g, (long)(2 * 128 + col) * DDIM + ks * 32 + quad * 8, isbf);
        #pragma unroll
        for (int m = 0; m < 2; ++m) ain[m] = MFMA16(fa[m], bw, ain[m]);
        // h-side: Whh r, z, n
        if constexpr (WSOK) bw = *reinterpret_cast<const bf16x8*>(ws_g + WS_HH_OFF + ((((wv * 3 + 0) * 4 + ks) * 64 + lane) << 3));
        else bw = ld8(whh_g, (long)(0 * 128 + col) * DDIM + ks * 32 + quad * 8, isbf);
        #pragma unroll
        for (int m = 0; m < 2; ++m) ar[m] = MFMA16(fh[m], bw, ar[m]);
        if constexpr (WSOK) bw = *reinterpret_cast<const bf16x8*>(ws_g + WS_HH_OFF + ((((wv * 3 + 1) * 4 + ks) * 64 + lane) << 3));
        else bw = ld8(whh_g, (long)(1 * 128 + col) * DDIM + ks * 32 + quad * 8, isbf);
        #pragma unroll
        for (int m = 0; m < 2; ++m) az[m] = MFMA16(fh[m], bw, az[m]);
        if constexpr (WSOK) bw = *reinterpret_cast<const bf16x8*>(ws_g + WS_HH_OFF + ((((wv * 3 + 2) * 4 + ks) * 64 + lane) << 3));
        else bw = ld8(whh_g, (long)(2 * 128 + col) * DDIM + ks * 32 + quad * 8, isbf);
        #pragma unroll
        for (int m = 0; m < 2; ++m) ahn[m] = MFMA16(fh[m], bw, ahn[m]);
      }
      // pointwise GRU + snew for this mt-pair
      #pragma unroll
      for (int m = 0; m < 2; ++m) {
        const int mt = p * 2 + m;
        #pragma unroll
        for (int pr = 0; pr < 2; ++pr) {
          const int e0 = pr * 2, e1 = pr * 2 + 1;
          float rg0 = sigm(ar[m][e0] + bsum_r), rg1 = sigm(ar[m][e1] + bsum_r);
          float zg0 = sigm(az[m][e0] + bsum_z), zg1 = sigm(az[m][e1] + bsum_z);
          float ng0 = tanh_f(ain[m][e0] + b_in + rg0 * (ahn[m][e0] + b_hn));
          float ng1 = tanh_f(ain[m][e1] + b_in + rg1 * (ahn[m][e1] + b_hn));
          unsigned int sp = sreg2[mt * 2 + pr], hp = hreg2[mt * 2 + pr];
          float sn0 = (1.0f - zg0) * ng0 + zg0 * bitsf(sp << 16) + bitsf(hp << 16);
          float sn1 = (1.0f - zg1) * ng1 + zg1 * bitsf(sp & 0xffff0000u) + bitsf(hp & 0xffff0000u);
          unsigned int pk = cvtpk(sn0, sn1);
          sreg2[mt * 2 + pr] = pk;
          const int rb = (mt * 16 + quad * 4 + pr * 2) * SD + col;
          s_m[rb     ] = (u16t)pk;
          s_m[rb + SD] = (u16t)(pk >> 16);
        }
      }
    }
    __syncthreads();  // (2) s_next ready
    u16t* t = s_c; s_c = s_m; s_m = s_a; s_a = t;  // rotate roles
  }

  // ---- readout: out[c] = sum_n (s@mlp2_w + b2)[n] * (s@mlp1_w + b1)[n][c] ----
  f32x4 oacc[4] = {{0,0,0,0},{0,0,0,0},{0,0,0,0},{0,0,0,0}};
  if (wv < 4) {
    #pragma unroll
    for (int ks = 0; ks < 4; ++ks) {
      bf16x8 bw;
      if constexpr (WSOK) {
        bw = *reinterpret_cast<const bf16x8*>(ws_g + WS_M1_OFF + (((wv * 4 + ks) * 64 + lane) << 3));
      } else {
        #pragma unroll
        for (int j = 0; j < 8; ++j)
          bw[j] = (short)f2bf(ldf(m1w_g, (long)(ks * 32 + quad * 8 + j) * 64 + col, isbf));
      }
      #pragma unroll
      for (int mt = 0; mt < 4; ++mt) {
        bf16x8 af = *reinterpret_cast<const bf16x8*>(s_c + (mt * 16 + lrow) * SD + ks * 32 + quad * 8);
        oacc[mt] = MFMA16(af, bw, oacc[mt]);
      }
    }
    const float b1c = ldf(m1b_g, col, isbf);
    #pragma unroll
    for (int mt = 0; mt < 4; ++mt)
      #pragma unroll
      for (int r = 0; r < 4; ++r) oacc[mt][r] += b1c;
  } else if (wv == 4) {
    float acc = 0.f;
    #pragma unroll
    for (int k = 0; k < 128; k += 8) {
      bf16x8 sv = *reinterpret_cast<const bf16x8*>(s_c + lane * SD + k);
      #pragma unroll
      for (int j = 0; j < 8; ++j) acc += bf2f((u16t)sv[j]) * ldf(m2w_g, k + j, isbf);
    }
    f_wv[lane] = acc + ldf(m2b_g, 0, isbf);
  }
  __syncthreads();
  if (wv < 4) {
    float p = 0.f;
    #pragma unroll
    for (int mt = 0; mt < 4; ++mt)
      #pragma unroll
      for (int r = 0; r < 4; ++r)
        p += f_wv[mt * 16 + quad * 4 + r] * oacc[mt][r];
    p += __shfl_xor(p, 16);
    p += __shfl_xor(p, 32);
    if (quad == 0) {
      if (isbf) ((u16t*)out_g)[(long)b * 64 + col] = f2bf(p);
      else      ((float*)out_g)[(long)b * 64 + col] = p;
    }
  }
}

extern "C" void kernel_launch(void* const* d_in, const int* in_sizes, int n_in,
                              void* d_out, int out_size, void* d_ws, size_t ws_size,
                              hipStream_t stream) {
  (void)in_sizes; (void)n_in; (void)out_size;
  // d_in order: h, adj(unused), a_src, a_dst, w, bias, W_ih, W_hh, b_ih, b_hh,
  //             mlp1_w, mlp1_b, mlp2_w, mlp2_b, steps
  const bool wsok = ws_size >= (size_t)WS_ELEMS * 2;
  if (wsok) {
    prep<<<dim3((WS_ELEMS + 255) / 256), dim3(256), 0, stream>>>(
        d_in[0], d_in[4], d_in[6], d_in[7], d_in[10], (u16t*)d_ws);
    fignn<true><<<dim3(4096), dim3(512), 0, stream>>>(
        d_in[0], d_in[2], d_in[3], d_in[4], d_in[5], d_in[6], d_in[7], d_in[8],
        d_in[9], d_in[10], d_in[11], d_in[12], d_in[13], (const int*)d_in[14],
        (const u16t*)d_ws, d_out);
  } else {
    fignn<false><<<dim3(4096), dim3(512), 0, stream>>>(
        d_in[0], d_in[2], d_in[3], d_in[4], d_in[5], d_in[6], d_in[7], d_in[8],
        d_in[9], d_in[10], d_in[11], d_in[12], d_in[13], (const int*)d_in[14],
        (const u16t*)d_ws, d_out);
  }
}